// Round 4
// baseline (383.169 us; speedup 1.0000x reference)
//
#include <hip/hip_runtime.h>
#include <stdint.h>

#define BATCH 524288
#define OBSD  64

typedef short v8s __attribute__((ext_vector_type(8)));
typedef float v4f __attribute__((ext_vector_type(4)));

union U8 { int4 i4; v8s v; uint32_t u[4]; };

__device__ __forceinline__ uint32_t bf16rne(float f) {
  uint32_t u = __float_as_uint(f);
  return (u + 0x7fffu + ((u >> 16) & 1u)) >> 16;
}
// gfx950 packed fp32->bf16 convert (RNE): D[15:0]=cvt(a), D[31:16]=cvt(b)
__device__ __forceinline__ uint32_t pk2(float a, float b) {
  uint32_t r;
  asm("v_cvt_pk_bf16_f32 %0, %1, %2" : "=v"(r) : "v"(a), "v"(b));
  return r;
}

// ---- prep: fp32 weights -> bf16 (W3p negated), zero welford accumulators ----
// Wall layout (elements): tW1@0(8192) tW2@8192(16384) tW3@24576(16384)
//                         pW1@40960(8192) pW2@49152(16384) -pW3@65536(16384)
__global__ void rnd_prep(const float* __restrict__ tW1, const float* __restrict__ tW2,
                         const float* __restrict__ tW3, const float* __restrict__ pW1,
                         const float* __restrict__ pW2, const float* __restrict__ pW3,
                         uint16_t* __restrict__ Wall, float* __restrict__ sums) {
  int i = blockIdx.x * 256 + threadIdx.x;  // grid covers exactly 81920
  if (i < 2) sums[i] = 0.0f;
  float v;
  if      (i < 8192)  v = tW1[i];
  else if (i < 24576) v = tW2[i - 8192];
  else if (i < 40960) v = tW3[i - 24576];
  else if (i < 49152) v = pW1[i - 40960];
  else if (i < 65536) v = pW2[i - 49152];
  else                v = -pW3[i - 65536];
  Wall[i] = (uint16_t)bf16rne(v);
}

// ---- main: R3 structure; packed-cvt epilogues, obs loaded once, 4 blocks/CU ----
__global__ __launch_bounds__(256, 4) void rnd_main(
    const float* __restrict__ obs, const uint16_t* __restrict__ Wall,
    const float* __restrict__ b1t, const float* __restrict__ b2t,
    const float* __restrict__ b1p, const float* __restrict__ b2p,
    const float* __restrict__ b3t, const float* __restrict__ b3p,
    float* __restrict__ rewards, float* __restrict__ sums) {
  __shared__ __align__(16) uint16_t Wbuf[128 * 136];  // 34 KB
  __shared__ float bs[4], bss[4];
  const int t    = threadIdx.x;
  const int lane = t & 63;
  const int wv   = t >> 6;
  const int n    = lane & 15;
  const int q    = lane >> 4;
  const int s0   = (blockIdx.x * 4 + wv) * 32;

  // ---- obs: issue global loads first (latency overlaps first staging) ----
  float4 of[8];
  #pragma unroll
  for (int ct = 0; ct < 2; ++ct)
    #pragma unroll
    for (int ks = 0; ks < 2; ++ks) {
      const float* p = obs + (size_t)(s0 + ct * 16 + n) * OBSD + ks * 32 + q * 8;
      of[(ct * 2 + ks) * 2 + 0] = *(const float4*)p;
      of[(ct * 2 + ks) * 2 + 1] = *(const float4*)(p + 4);
    }

  // ---- staging: plain padded copy ----
  auto stage64 = [&](const uint16_t* src) {   // 128x64, Kp=72
    #pragma unroll
    for (int i = 0; i < 4; ++i) {
      int g = i * 256 + t;
      int d = g >> 3, c = g & 7;
      U8 u; u.i4 = *(const int4*)(src + g * 8);
      *(int4*)(Wbuf + d * 72 + c * 8) = u.i4;
    }
  };
  auto stage128 = [&](const uint16_t* src) {  // 128x128, Kp=136
    #pragma unroll
    for (int i = 0; i < 8; ++i) {
      int g = i * 256 + t;
      int d = g >> 4, c = g & 15;
      U8 u; u.i4 = *(const int4*)(src + g * 8);
      *(int4*)(Wbuf + d * 136 + c * 8) = u.i4;
    }
  };
  auto afragL = [&](int Kp, int rt, int ks) -> v8s {
    U8 u; u.i4 = *(const int4*)(Wbuf + (rt * 16 + n) * Kp + ks * 32 + q * 8);
    return u.v;
  };

  auto bias_init = [&](const float* b, v4f (&acc)[8][2]) {
    #pragma unroll
    for (int rt = 0; rt < 8; ++rt) {
      float4 bv = *(const float4*)(b + rt * 16 + q * 4);
      v4f c; c[0] = bv.x; c[1] = bv.y; c[2] = bv.z; c[3] = bv.w;
      acc[rt][0] = c; acc[rt][1] = c;
    }
  };
  auto pack_out = [&](v4f (&acc)[8][2], uint32_t (&P)[8][2][2]) {
    #pragma unroll
    for (int rt = 0; rt < 8; ++rt)
      #pragma unroll
      for (int ct = 0; ct < 2; ++ct) {
        v4f a = acc[rt][ct];
        a[0] = fmaxf(a[0], 0.f); a[1] = fmaxf(a[1], 0.f);
        a[2] = fmaxf(a[2], 0.f); a[3] = fmaxf(a[3], 0.f);
        P[rt][ct][0] = pk2(a[0], a[1]);
        P[rt][ct][1] = pk2(a[2], a[3]);
      }
  };
  // C-layout -> B-operand layout via cross-lane swaps (proven R1/R3)
  auto bfrag_from = [&](uint32_t (&P)[8][2][2], int ks, int ct) -> v8s {
    uint32_t x0 = P[2 * ks][ct][0],     x1 = P[2 * ks][ct][1];
    uint32_t y0 = P[2 * ks + 1][ct][0], y1 = P[2 * ks + 1][ct][1];
    asm("v_permlane32_swap_b32 %0, %1" : "+v"(x0), "+v"(y0));
    asm("v_permlane16_swap_b32 %0, %1" : "+v"(x0), "+v"(y0));
    asm("v_permlane32_swap_b32 %0, %1" : "+v"(x1), "+v"(y1));
    asm("v_permlane16_swap_b32 %0, %1" : "+v"(x1), "+v"(y1));
    U8 u; u.u[0] = x0; u.u[1] = x1; u.u[2] = y0; u.u[3] = y1;
    return u.v;
  };

  // ---- pack obs once (shared by both nets) ----
  v8s obf[2][2];
  #pragma unroll
  for (int ct = 0; ct < 2; ++ct)
    #pragma unroll
    for (int ks = 0; ks < 2; ++ks) {
      float4 f0 = of[(ct * 2 + ks) * 2 + 0];
      float4 f1 = of[(ct * 2 + ks) * 2 + 1];
      U8 u;
      u.u[0] = pk2(f0.x, f0.y); u.u[1] = pk2(f0.z, f0.w);
      u.u[2] = pk2(f1.x, f1.y); u.u[3] = pk2(f1.z, f1.w);
      obf[ct][ks] = u.v;
    }

  auto layer1 = [&](const float* b, uint32_t (&P)[8][2][2]) {
    v4f acc[8][2];
    bias_init(b, acc);
    #pragma unroll
    for (int ks = 0; ks < 2; ++ks) {
      #pragma unroll
      for (int rt = 0; rt < 8; ++rt) {
        v8s af = afragL(72, rt, ks);
        acc[rt][0] = __builtin_amdgcn_mfma_f32_16x16x32_bf16(af, obf[0][ks], acc[rt][0], 0, 0, 0);
        acc[rt][1] = __builtin_amdgcn_mfma_f32_16x16x32_bf16(af, obf[1][ks], acc[rt][1], 0, 0, 0);
      }
    }
    pack_out(acc, P);
  };
  auto layer2 = [&](const float* b, uint32_t (&Pin)[8][2][2], uint32_t (&Pout)[8][2][2]) {
    v4f acc[8][2];
    bias_init(b, acc);
    #pragma unroll
    for (int ks = 0; ks < 4; ++ks) {
      v8s bf0 = bfrag_from(Pin, ks, 0), bf1 = bfrag_from(Pin, ks, 1);
      #pragma unroll
      for (int rt = 0; rt < 8; ++rt) {
        v8s af = afragL(136, rt, ks);
        acc[rt][0] = __builtin_amdgcn_mfma_f32_16x16x32_bf16(af, bf0, acc[rt][0], 0, 0, 0);
        acc[rt][1] = __builtin_amdgcn_mfma_f32_16x16x32_bf16(af, bf1, acc[rt][1], 0, 0, 0);
      }
    }
    pack_out(acc, Pout);  // safe when Pout==Pin: all reads precede writes
  };

  uint32_t Pa[8][2][2];
  uint32_t Pt[8][2][2];

  // ---- target net ----
  stage64(Wall + 0);        __syncthreads();
  layer1(b1t, Pa);          __syncthreads();
  stage128(Wall + 8192);    __syncthreads();
  layer2(b2t, Pa, Pt);      __syncthreads();
  // ---- predictor net ----
  stage64(Wall + 40960);    __syncthreads();
  layer1(b1p, Pa);          __syncthreads();
  stage128(Wall + 49152);   __syncthreads();
  layer2(b2p, Pa, Pa);      __syncthreads();

  // ---- final layer: acc = (b3t-b3p) + W3t*H2t + (-W3p)*H2p == y_t - y_p ----
  v4f acc[8][2];
  #pragma unroll
  for (int rt = 0; rt < 8; ++rt) {
    float4 bt = *(const float4*)(b3t + rt * 16 + q * 4);
    float4 bp = *(const float4*)(b3p + rt * 16 + q * 4);
    v4f c; c[0] = bt.x - bp.x; c[1] = bt.y - bp.y; c[2] = bt.z - bp.z; c[3] = bt.w - bp.w;
    acc[rt][0] = c; acc[rt][1] = c;
  }
  stage128(Wall + 24576);   __syncthreads();
  #pragma unroll
  for (int ks = 0; ks < 4; ++ks) {
    v8s bf0 = bfrag_from(Pt, ks, 0), bf1 = bfrag_from(Pt, ks, 1);
    #pragma unroll
    for (int rt = 0; rt < 8; ++rt) {
      v8s af = afragL(136, rt, ks);
      acc[rt][0] = __builtin_amdgcn_mfma_f32_16x16x32_bf16(af, bf0, acc[rt][0], 0, 0, 0);
      acc[rt][1] = __builtin_amdgcn_mfma_f32_16x16x32_bf16(af, bf1, acc[rt][1], 0, 0, 0);
    }
  }
  __syncthreads();
  stage128(Wall + 65536);   __syncthreads();
  #pragma unroll
  for (int ks = 0; ks < 4; ++ks) {
    v8s bf0 = bfrag_from(Pa, ks, 0), bf1 = bfrag_from(Pa, ks, 1);
    #pragma unroll
    for (int rt = 0; rt < 8; ++rt) {
      v8s af = afragL(136, rt, ks);
      acc[rt][0] = __builtin_amdgcn_mfma_f32_16x16x32_bf16(af, bf0, acc[rt][0], 0, 0, 0);
      acc[rt][1] = __builtin_amdgcn_mfma_f32_16x16x32_bf16(af, bf1, acc[rt][1], 0, 0, 0);
    }
  }

  // ---- epilogue: reward = mean over 128 out-dims of diff^2 ----
  float p0 = 0.f, p1 = 0.f;
  #pragma unroll
  for (int rt = 0; rt < 8; ++rt) {
    v4f a0 = acc[rt][0], a1 = acc[rt][1];
    p0 += a0[0]*a0[0] + a0[1]*a0[1] + a0[2]*a0[2] + a0[3]*a0[3];
    p1 += a1[0]*a1[0] + a1[1]*a1[1] + a1[2]*a1[2] + a1[3]*a1[3];
  }
  p0 += __shfl_xor(p0, 32); p0 += __shfl_xor(p0, 16);
  p1 += __shfl_xor(p1, 32); p1 += __shfl_xor(p1, 16);
  float r0 = p0 * (1.0f / 128.0f), r1 = p1 * (1.0f / 128.0f);
  if (q == 0) {
    rewards[s0 + n]      = r0;
    rewards[s0 + 16 + n] = r1;
  }
  float s = r0 + r1, ss = r0 * r0 + r1 * r1;
  s  += __shfl_xor(s, 8);  s  += __shfl_xor(s, 4);  s  += __shfl_xor(s, 2);  s  += __shfl_xor(s, 1);
  ss += __shfl_xor(ss, 8); ss += __shfl_xor(ss, 4); ss += __shfl_xor(ss, 2); ss += __shfl_xor(ss, 1);
  if (lane == 0) { bs[wv] = s; bss[wv] = ss; }
  __syncthreads();
  if (t == 0) {
    atomicAdd(&sums[0], bs[0] + bs[1] + bs[2] + bs[3]);
    atomicAdd(&sums[1], bss[0] + bss[1] + bss[2] + bss[3]);
  }
}

// ---- normalize: Chan-merge with running stats ----
__global__ void rnd_norm(const float* __restrict__ rewards, const float* __restrict__ sums,
                         const float* __restrict__ rm, const float* __restrict__ rm2,
                         const float* __restrict__ rc, float* __restrict__ out) {
  float S = sums[0], SS = sums[1];
  float nb = (float)BATCH;
  float bm = S / nb;
  float bm2 = SS - nb * bm * bm;
  float cnt = rc[0];
  float newc = cnt + nb;
  float delta = bm - rm[0];
  float newmean = rm[0] + delta * nb / newc;
  float newm2 = rm2[0] + bm2 + delta * delta * cnt * nb / newc;
  float sd = (newc > 1.f) ? sqrtf(newm2 / (newc - 1.f)) : 1.f;
  float inv = 1.f / (sd + 1e-8f);
  int i = (blockIdx.x * 256 + threadIdx.x) * 4;
  float4 r = *(const float4*)(rewards + i);
  float4 o;
  o.x = (r.x - newmean) * inv; o.y = (r.y - newmean) * inv;
  o.z = (r.z - newmean) * inv; o.w = (r.w - newmean) * inv;
  *(float4*)(out + i) = o;
}

extern "C" void kernel_launch(void* const* d_in, const int* in_sizes, int n_in,
                              void* d_out, int out_size, void* d_ws, size_t ws_size,
                              hipStream_t stream) {
  const float* obs = (const float*)d_in[0];
  const float* rm  = (const float*)d_in[1];
  const float* rm2 = (const float*)d_in[2];
  const float* rc  = (const float*)d_in[3];
  const float* tW1 = (const float*)d_in[4];
  const float* tb1 = (const float*)d_in[5];
  const float* tW2 = (const float*)d_in[6];
  const float* tb2 = (const float*)d_in[7];
  const float* tW3 = (const float*)d_in[8];
  const float* tb3 = (const float*)d_in[9];
  const float* pW1 = (const float*)d_in[10];
  const float* pb1 = (const float*)d_in[11];
  const float* pW2 = (const float*)d_in[12];
  const float* pb2 = (const float*)d_in[13];
  const float* pW3 = (const float*)d_in[14];
  const float* pb3 = (const float*)d_in[15];

  float*    sums    = (float*)d_ws;
  float*    rewards = (float*)((char*)d_ws + 256);
  uint16_t* Wall    = (uint16_t*)((char*)d_ws + 256 + (size_t)BATCH * 4);

  rnd_prep<<<320, 256, 0, stream>>>(tW1, tW2, tW3, pW1, pW2, pW3, Wall, sums);
  rnd_main<<<BATCH / 128, 256, 0, stream>>>(obs, Wall, tb1, tb2, pb1, pb2, tb3, pb3,
                                            rewards, sums);
  rnd_norm<<<BATCH / 1024, 256, 0, stream>>>(rewards, sums, rm, rm2, rc, (float*)d_out);
}

// Round 5
// 336.490 us; speedup vs baseline: 1.1387x; 1.1387x over previous
//
#include <hip/hip_runtime.h>
#include <stdint.h>

#define BATCH 524288
#define OBSD  64

typedef short v8s __attribute__((ext_vector_type(8)));
typedef float v4f __attribute__((ext_vector_type(4)));

union U8 { int4 i4; v8s v; uint32_t u[4]; };

__device__ __forceinline__ uint32_t bf16rne(float f) {
  uint32_t u = __float_as_uint(f);
  return (u + 0x7fffu + ((u >> 16) & 1u)) >> 16;
}
// gfx950 packed fp32->bf16 convert (RNE): D[15:0]=cvt(a), D[31:16]=cvt(b)
__device__ __forceinline__ uint32_t pk2(float a, float b) {
  uint32_t r;
  asm("v_cvt_pk_bf16_f32 %0, %1, %2" : "=v"(r) : "v"(a), "v"(b));
  return r;
}

// ---- prep: fp32 weights -> bf16 (W3p negated), zero welford accumulators ----
// Wall layout (elements): tW1@0(8192) tW2@8192(16384) tW3@24576(16384)
//                         pW1@40960(8192) pW2@49152(16384) -pW3@65536(16384)
__global__ void rnd_prep(const float* __restrict__ tW1, const float* __restrict__ tW2,
                         const float* __restrict__ tW3, const float* __restrict__ pW1,
                         const float* __restrict__ pW2, const float* __restrict__ pW3,
                         uint16_t* __restrict__ Wall, float* __restrict__ sums) {
  int i = blockIdx.x * 256 + threadIdx.x;  // grid covers exactly 81920
  if (i < 2) sums[i] = 0.0f;
  float v;
  if      (i < 8192)  v = tW1[i];
  else if (i < 24576) v = tW2[i - 8192];
  else if (i < 40960) v = tW3[i - 24576];
  else if (i < 49152) v = pW1[i - 40960];
  else if (i < 65536) v = pW2[i - 49152];
  else                v = -pW3[i - 65536];
  Wall[i] = (uint16_t)bf16rne(v);
}

// ---- main: R3 schedule; packed-cvt epilogues, obs loaded once, 3 blocks/CU ----
// (R4 post-mortem: launch_bounds(256,4) caps unified VGPR at 128 -> 430MB of
//  scratch spill traffic. 3 blocks/CU = 170-reg budget, 148 used, no spills.)
__global__ __launch_bounds__(256, 3) void rnd_main(
    const float* __restrict__ obs, const uint16_t* __restrict__ Wall,
    const float* __restrict__ b1t, const float* __restrict__ b2t,
    const float* __restrict__ b1p, const float* __restrict__ b2p,
    const float* __restrict__ b3t, const float* __restrict__ b3p,
    float* __restrict__ rewards, float* __restrict__ sums) {
  __shared__ __align__(16) uint16_t Wbuf[128 * 136];  // 34 KB
  __shared__ float bs[4], bss[4];
  const int t    = threadIdx.x;
  const int lane = t & 63;
  const int wv   = t >> 6;
  const int n    = lane & 15;
  const int q    = lane >> 4;
  const int s0   = (blockIdx.x * 4 + wv) * 32;

  // ---- staging: plain padded copy ----
  auto stage64 = [&](const uint16_t* src) {   // 128x64, Kp=72
    #pragma unroll
    for (int i = 0; i < 4; ++i) {
      int g = i * 256 + t;
      int d = g >> 3, c = g & 7;
      U8 u; u.i4 = *(const int4*)(src + g * 8);
      *(int4*)(Wbuf + d * 72 + c * 8) = u.i4;
    }
  };
  auto stage128 = [&](const uint16_t* src) {  // 128x128, Kp=136
    #pragma unroll
    for (int i = 0; i < 8; ++i) {
      int g = i * 256 + t;
      int d = g >> 4, c = g & 15;
      U8 u; u.i4 = *(const int4*)(src + g * 8);
      *(int4*)(Wbuf + d * 136 + c * 8) = u.i4;
    }
  };
  auto afragL = [&](int Kp, int rt, int ks) -> v8s {
    U8 u; u.i4 = *(const int4*)(Wbuf + (rt * 16 + n) * Kp + ks * 32 + q * 8);
    return u.v;
  };

  // ---- obs: issue global loads, then first staging, THEN pack (overlap) ----
  float4 of[8];
  #pragma unroll
  for (int ct = 0; ct < 2; ++ct)
    #pragma unroll
    for (int ks = 0; ks < 2; ++ks) {
      const float* p = obs + (size_t)(s0 + ct * 16 + n) * OBSD + ks * 32 + q * 8;
      of[(ct * 2 + ks) * 2 + 0] = *(const float4*)p;
      of[(ct * 2 + ks) * 2 + 1] = *(const float4*)(p + 4);
    }
  stage64(Wall + 0);  // W1t staging loads in flight before obs pack waits

  v8s obf[2][2];
  #pragma unroll
  for (int ct = 0; ct < 2; ++ct)
    #pragma unroll
    for (int ks = 0; ks < 2; ++ks) {
      float4 f0 = of[(ct * 2 + ks) * 2 + 0];
      float4 f1 = of[(ct * 2 + ks) * 2 + 1];
      U8 u;
      u.u[0] = pk2(f0.x, f0.y); u.u[1] = pk2(f0.z, f0.w);
      u.u[2] = pk2(f1.x, f1.y); u.u[3] = pk2(f1.z, f1.w);
      obf[ct][ks] = u.v;
    }

  auto bias_init = [&](const float* b, v4f (&acc)[8][2]) {
    #pragma unroll
    for (int rt = 0; rt < 8; ++rt) {
      float4 bv = *(const float4*)(b + rt * 16 + q * 4);
      v4f c; c[0] = bv.x; c[1] = bv.y; c[2] = bv.z; c[3] = bv.w;
      acc[rt][0] = c; acc[rt][1] = c;
    }
  };
  auto pack_out = [&](v4f (&acc)[8][2], uint32_t (&P)[8][2][2]) {
    #pragma unroll
    for (int rt = 0; rt < 8; ++rt)
      #pragma unroll
      for (int ct = 0; ct < 2; ++ct) {
        v4f a = acc[rt][ct];
        a[0] = fmaxf(a[0], 0.f); a[1] = fmaxf(a[1], 0.f);
        a[2] = fmaxf(a[2], 0.f); a[3] = fmaxf(a[3], 0.f);
        P[rt][ct][0] = pk2(a[0], a[1]);
        P[rt][ct][1] = pk2(a[2], a[3]);
      }
  };
  // C-layout -> B-operand layout via cross-lane swaps (proven R1/R3)
  auto bfrag_from = [&](uint32_t (&P)[8][2][2], int ks, int ct) -> v8s {
    uint32_t x0 = P[2 * ks][ct][0],     x1 = P[2 * ks][ct][1];
    uint32_t y0 = P[2 * ks + 1][ct][0], y1 = P[2 * ks + 1][ct][1];
    asm("v_permlane32_swap_b32 %0, %1" : "+v"(x0), "+v"(y0));
    asm("v_permlane16_swap_b32 %0, %1" : "+v"(x0), "+v"(y0));
    asm("v_permlane32_swap_b32 %0, %1" : "+v"(x1), "+v"(y1));
    asm("v_permlane16_swap_b32 %0, %1" : "+v"(x1), "+v"(y1));
    U8 u; u.u[0] = x0; u.u[1] = x1; u.u[2] = y0; u.u[3] = y1;
    return u.v;
  };

  auto layer1 = [&](const float* b, uint32_t (&P)[8][2][2]) {
    v4f acc[8][2];
    bias_init(b, acc);
    #pragma unroll
    for (int ks = 0; ks < 2; ++ks) {
      #pragma unroll
      for (int rt = 0; rt < 8; ++rt) {
        v8s af = afragL(72, rt, ks);
        acc[rt][0] = __builtin_amdgcn_mfma_f32_16x16x32_bf16(af, obf[0][ks], acc[rt][0], 0, 0, 0);
        acc[rt][1] = __builtin_amdgcn_mfma_f32_16x16x32_bf16(af, obf[1][ks], acc[rt][1], 0, 0, 0);
      }
    }
    pack_out(acc, P);
  };
  auto layer2 = [&](const float* b, uint32_t (&Pin)[8][2][2], uint32_t (&Pout)[8][2][2]) {
    v4f acc[8][2];
    bias_init(b, acc);
    #pragma unroll
    for (int ks = 0; ks < 4; ++ks) {
      v8s bf0 = bfrag_from(Pin, ks, 0), bf1 = bfrag_from(Pin, ks, 1);
      #pragma unroll
      for (int rt = 0; rt < 8; ++rt) {
        v8s af = afragL(136, rt, ks);
        acc[rt][0] = __builtin_amdgcn_mfma_f32_16x16x32_bf16(af, bf0, acc[rt][0], 0, 0, 0);
        acc[rt][1] = __builtin_amdgcn_mfma_f32_16x16x32_bf16(af, bf1, acc[rt][1], 0, 0, 0);
      }
    }
    pack_out(acc, Pout);  // safe when Pout==Pin: all reads precede writes
  };

  uint32_t Pa[8][2][2];
  uint32_t Pt[8][2][2];

  // ---- target net ----
  __syncthreads();          // stage64(W1t) done
  layer1(b1t, Pa);          __syncthreads();
  stage128(Wall + 8192);    __syncthreads();
  layer2(b2t, Pa, Pt);      __syncthreads();
  // ---- predictor net ----
  stage64(Wall + 40960);    __syncthreads();
  layer1(b1p, Pa);          __syncthreads();
  stage128(Wall + 49152);   __syncthreads();
  layer2(b2p, Pa, Pa);      __syncthreads();

  // ---- final layer: acc = (b3t-b3p) + W3t*H2t + (-W3p)*H2p == y_t - y_p ----
  v4f acc[8][2];
  #pragma unroll
  for (int rt = 0; rt < 8; ++rt) {
    float4 bt = *(const float4*)(b3t + rt * 16 + q * 4);
    float4 bp = *(const float4*)(b3p + rt * 16 + q * 4);
    v4f c; c[0] = bt.x - bp.x; c[1] = bt.y - bp.y; c[2] = bt.z - bp.z; c[3] = bt.w - bp.w;
    acc[rt][0] = c; acc[rt][1] = c;
  }
  stage128(Wall + 24576);   __syncthreads();
  #pragma unroll
  for (int ks = 0; ks < 4; ++ks) {
    v8s bf0 = bfrag_from(Pt, ks, 0), bf1 = bfrag_from(Pt, ks, 1);
    #pragma unroll
    for (int rt = 0; rt < 8; ++rt) {
      v8s af = afragL(136, rt, ks);
      acc[rt][0] = __builtin_amdgcn_mfma_f32_16x16x32_bf16(af, bf0, acc[rt][0], 0, 0, 0);
      acc[rt][1] = __builtin_amdgcn_mfma_f32_16x16x32_bf16(af, bf1, acc[rt][1], 0, 0, 0);
    }
  }
  __syncthreads();
  stage128(Wall + 65536);   __syncthreads();
  #pragma unroll
  for (int ks = 0; ks < 4; ++ks) {
    v8s bf0 = bfrag_from(Pa, ks, 0), bf1 = bfrag_from(Pa, ks, 1);
    #pragma unroll
    for (int rt = 0; rt < 8; ++rt) {
      v8s af = afragL(136, rt, ks);
      acc[rt][0] = __builtin_amdgcn_mfma_f32_16x16x32_bf16(af, bf0, acc[rt][0], 0, 0, 0);
      acc[rt][1] = __builtin_amdgcn_mfma_f32_16x16x32_bf16(af, bf1, acc[rt][1], 0, 0, 0);
    }
  }

  // ---- epilogue: reward = mean over 128 out-dims of diff^2 ----
  float p0 = 0.f, p1 = 0.f;
  #pragma unroll
  for (int rt = 0; rt < 8; ++rt) {
    v4f a0 = acc[rt][0], a1 = acc[rt][1];
    p0 += a0[0]*a0[0] + a0[1]*a0[1] + a0[2]*a0[2] + a0[3]*a0[3];
    p1 += a1[0]*a1[0] + a1[1]*a1[1] + a1[2]*a1[2] + a1[3]*a1[3];
  }
  p0 += __shfl_xor(p0, 32); p0 += __shfl_xor(p0, 16);
  p1 += __shfl_xor(p1, 32); p1 += __shfl_xor(p1, 16);
  float r0 = p0 * (1.0f / 128.0f), r1 = p1 * (1.0f / 128.0f);
  if (q == 0) {
    rewards[s0 + n]      = r0;
    rewards[s0 + 16 + n] = r1;
  }
  float s = r0 + r1, ss = r0 * r0 + r1 * r1;
  s  += __shfl_xor(s, 8);  s  += __shfl_xor(s, 4);  s  += __shfl_xor(s, 2);  s  += __shfl_xor(s, 1);
  ss += __shfl_xor(ss, 8); ss += __shfl_xor(ss, 4); ss += __shfl_xor(ss, 2); ss += __shfl_xor(ss, 1);
  if (lane == 0) { bs[wv] = s; bss[wv] = ss; }
  __syncthreads();
  if (t == 0) {
    atomicAdd(&sums[0], bs[0] + bs[1] + bs[2] + bs[3]);
    atomicAdd(&sums[1], bss[0] + bss[1] + bss[2] + bss[3]);
  }
}

// ---- normalize: Chan-merge with running stats ----
__global__ void rnd_norm(const float* __restrict__ rewards, const float* __restrict__ sums,
                         const float* __restrict__ rm, const float* __restrict__ rm2,
                         const float* __restrict__ rc, float* __restrict__ out) {
  float S = sums[0], SS = sums[1];
  float nb = (float)BATCH;
  float bm = S / nb;
  float bm2 = SS - nb * bm * bm;
  float cnt = rc[0];
  float newc = cnt + nb;
  float delta = bm - rm[0];
  float newmean = rm[0] + delta * nb / newc;
  float newm2 = rm2[0] + bm2 + delta * delta * cnt * nb / newc;
  float sd = (newc > 1.f) ? sqrtf(newm2 / (newc - 1.f)) : 1.f;
  float inv = 1.f / (sd + 1e-8f);
  int i = (blockIdx.x * 256 + threadIdx.x) * 4;
  float4 r = *(const float4*)(rewards + i);
  float4 o;
  o.x = (r.x - newmean) * inv; o.y = (r.y - newmean) * inv;
  o.z = (r.z - newmean) * inv; o.w = (r.w - newmean) * inv;
  *(float4*)(out + i) = o;
}

extern "C" void kernel_launch(void* const* d_in, const int* in_sizes, int n_in,
                              void* d_out, int out_size, void* d_ws, size_t ws_size,
                              hipStream_t stream) {
  const float* obs = (const float*)d_in[0];
  const float* rm  = (const float*)d_in[1];
  const float* rm2 = (const float*)d_in[2];
  const float* rc  = (const float*)d_in[3];
  const float* tW1 = (const float*)d_in[4];
  const float* tb1 = (const float*)d_in[5];
  const float* tW2 = (const float*)d_in[6];
  const float* tb2 = (const float*)d_in[7];
  const float* tW3 = (const float*)d_in[8];
  const float* tb3 = (const float*)d_in[9];
  const float* pW1 = (const float*)d_in[10];
  const float* pb1 = (const float*)d_in[11];
  const float* pW2 = (const float*)d_in[12];
  const float* pb2 = (const float*)d_in[13];
  const float* pW3 = (const float*)d_in[14];
  const float* pb3 = (const float*)d_in[15];

  float*    sums    = (float*)d_ws;
  float*    rewards = (float*)((char*)d_ws + 256);
  uint16_t* Wall    = (uint16_t*)((char*)d_ws + 256 + (size_t)BATCH * 4);

  rnd_prep<<<320, 256, 0, stream>>>(tW1, tW2, tW3, pW1, pW2, pW3, Wall, sums);
  rnd_main<<<BATCH / 128, 256, 0, stream>>>(obs, Wall, tb1, tb2, pb1, pb2, tb3, pb3,
                                            rewards, sums);
  rnd_norm<<<BATCH / 1024, 256, 0, stream>>>(rewards, sums, rm, rm2, rc, (float*)d_out);
}

// Round 6
// 331.807 us; speedup vs baseline: 1.1548x; 1.0141x over previous
//
#include <hip/hip_runtime.h>
#include <stdint.h>

#define BATCH 524288
#define OBSD  64

typedef short v8s __attribute__((ext_vector_type(8)));
typedef float v4f __attribute__((ext_vector_type(4)));

union U8 { int4 i4; v8s v; uint32_t u[4]; };

__device__ __forceinline__ uint32_t bf16rne(float f) {
  uint32_t u = __float_as_uint(f);
  return (u + 0x7fffu + ((u >> 16) & 1u)) >> 16;
}
// gfx950 packed fp32->bf16 convert (RNE)
__device__ __forceinline__ uint32_t pk2(float a, float b) {
  uint32_t r;
  asm("v_cvt_pk_bf16_f32 %0, %1, %2" : "=v"(r) : "v"(a), "v"(b));
  return r;
}

// ---- prep: fp32 weights -> bf16 (W3p negated), zero welford accumulators ----
// Wall layout (elements): tW1@0(8192) tW2@8192(16384) tW3@24576(16384)
//                         pW1@40960(8192) pW2@49152(16384) -pW3@65536(16384)
__global__ void rnd_prep(const float* __restrict__ tW1, const float* __restrict__ tW2,
                         const float* __restrict__ tW3, const float* __restrict__ pW1,
                         const float* __restrict__ pW2, const float* __restrict__ pW3,
                         uint16_t* __restrict__ Wall, float* __restrict__ sums) {
  int i = blockIdx.x * 256 + threadIdx.x;  // grid covers exactly 81920
  if (i < 2) sums[i] = 0.0f;
  float v;
  if      (i < 8192)  v = tW1[i];
  else if (i < 24576) v = tW2[i - 8192];
  else if (i < 40960) v = tW3[i - 24576];
  else if (i < 49152) v = pW1[i - 40960];
  else if (i < 65536) v = pW2[i - 49152];
  else                v = -pW3[i - 65536];
  Wall[i] = (uint16_t)bf16rne(v);
}

// ---- main: R5 schedule; hoisted addressing (immediate LDS offsets),
//      merged W1t+W1p staging (10 barriers), 3 blocks/CU ----
__global__ __launch_bounds__(256, 3) void rnd_main(
    const float* __restrict__ obs, const uint16_t* __restrict__ Wall,
    const float* __restrict__ b1t, const float* __restrict__ b2t,
    const float* __restrict__ b1p, const float* __restrict__ b2p,
    const float* __restrict__ b3t, const float* __restrict__ b3p,
    float* __restrict__ rewards, float* __restrict__ sums) {
  __shared__ __align__(16) uint16_t Wbuf[128 * 144];  // 36,864 B
  __shared__ float bs[4], bss[4];
  const int t    = threadIdx.x;
  const int lane = t & 63;
  const int wv   = t >> 6;
  const int n    = lane & 15;
  const int q    = lane >> 4;
  const int s0   = (blockIdx.x * 4 + wv) * 32;

  // ---- per-thread base pointers (computed once; all accesses use imm offsets)
  uint16_t*       sw1      = Wbuf + (t >> 3) * 72  + (t & 7)  * 8;  // W1 stage write
  uint16_t*       sw2      = Wbuf + (t >> 4) * 136 + (t & 15) * 8;  // 128x128 stage write
  const uint16_t* abase72  = Wbuf + n * 72  + q * 8;                // L1 A-frag read
  const uint16_t* abase136 = Wbuf + n * 136 + q * 8;                // L2/L3 A-frag read

  // ---- issue obs loads, then W1-pair staging loads, then pack obs ----
  float4 of[8];
  #pragma unroll
  for (int ct = 0; ct < 2; ++ct)
    #pragma unroll
    for (int ks = 0; ks < 2; ++ks) {
      const float* p = obs + (size_t)(s0 + ct * 16 + n) * OBSD + ks * 32 + q * 8;
      of[(ct * 2 + ks) * 2 + 0] = *(const float4*)p;
      of[(ct * 2 + ks) * 2 + 1] = *(const float4*)(p + 4);
    }
  int4 w1a[4], w1b[4];
  {
    const uint16_t* g0 = Wall + t * 8;          // tW1
    const uint16_t* g1 = Wall + 40960 + t * 8;  // pW1
    #pragma unroll
    for (int i = 0; i < 4; ++i) w1a[i] = *(const int4*)(g0 + i * 2048);
    #pragma unroll
    for (int i = 0; i < 4; ++i) w1b[i] = *(const int4*)(g1 + i * 2048);
  }
  v8s obf[2][2];
  #pragma unroll
  for (int ct = 0; ct < 2; ++ct)
    #pragma unroll
    for (int ks = 0; ks < 2; ++ks) {
      float4 f0 = of[(ct * 2 + ks) * 2 + 0];
      float4 f1 = of[(ct * 2 + ks) * 2 + 1];
      U8 u;
      u.u[0] = pk2(f0.x, f0.y); u.u[1] = pk2(f0.z, f0.w);
      u.u[2] = pk2(f1.x, f1.y); u.u[3] = pk2(f1.z, f1.w);
      obf[ct][ks] = u.v;
    }
  #pragma unroll
  for (int i = 0; i < 4; ++i) *(int4*)(sw1 + i * 2304) = w1a[i];
  #pragma unroll
  for (int i = 0; i < 4; ++i) *(int4*)(sw1 + 9216 + i * 2304) = w1b[i];

  auto stage128 = [&](const uint16_t* src) {  // 128x128 -> Wbuf, Kp=136
    const uint16_t* g = src + t * 8;
    int4 tmp[8];
    #pragma unroll
    for (int i = 0; i < 8; ++i) tmp[i] = *(const int4*)(g + i * 2048);
    #pragma unroll
    for (int i = 0; i < 8; ++i) *(int4*)(sw2 + i * 2176) = tmp[i];
  };
  auto afrag72 = [&](int sub, int rt, int ks) -> v8s {   // sub/rt/ks constants
    U8 u; u.i4 = *(const int4*)(abase72 + sub + rt * 1152 + ks * 32);
    return u.v;
  };
  auto afrag136 = [&](int rt, int ks) -> v8s {
    U8 u; u.i4 = *(const int4*)(abase136 + rt * 2176 + ks * 32);
    return u.v;
  };

  auto bias_init = [&](const float* b, v4f (&acc)[8][2]) {
    #pragma unroll
    for (int rt = 0; rt < 8; ++rt) {
      float4 bv = *(const float4*)(b + rt * 16 + q * 4);
      v4f c; c[0] = bv.x; c[1] = bv.y; c[2] = bv.z; c[3] = bv.w;
      acc[rt][0] = c; acc[rt][1] = c;
    }
  };
  auto pack_out = [&](v4f (&acc)[8][2], uint32_t (&P)[8][2][2]) {
    #pragma unroll
    for (int rt = 0; rt < 8; ++rt)
      #pragma unroll
      for (int ct = 0; ct < 2; ++ct) {
        v4f a = acc[rt][ct];
        a[0] = fmaxf(a[0], 0.f); a[1] = fmaxf(a[1], 0.f);
        a[2] = fmaxf(a[2], 0.f); a[3] = fmaxf(a[3], 0.f);
        P[rt][ct][0] = pk2(a[0], a[1]);
        P[rt][ct][1] = pk2(a[2], a[3]);
      }
  };
  // C-layout -> B-operand layout via cross-lane swaps (proven R1/R3/R5)
  auto bfrag_from = [&](uint32_t (&P)[8][2][2], int ks, int ct) -> v8s {
    uint32_t x0 = P[2 * ks][ct][0],     x1 = P[2 * ks][ct][1];
    uint32_t y0 = P[2 * ks + 1][ct][0], y1 = P[2 * ks + 1][ct][1];
    asm("v_permlane32_swap_b32 %0, %1" : "+v"(x0), "+v"(y0));
    asm("v_permlane16_swap_b32 %0, %1" : "+v"(x0), "+v"(y0));
    asm("v_permlane32_swap_b32 %0, %1" : "+v"(x1), "+v"(y1));
    asm("v_permlane16_swap_b32 %0, %1" : "+v"(x1), "+v"(y1));
    U8 u; u.u[0] = x0; u.u[1] = x1; u.u[2] = y0; u.u[3] = y1;
    return u.v;
  };

  auto layer1 = [&](int sub, const float* b, uint32_t (&P)[8][2][2]) {
    v4f acc[8][2];
    bias_init(b, acc);
    #pragma unroll
    for (int ks = 0; ks < 2; ++ks) {
      #pragma unroll
      for (int rt = 0; rt < 8; ++rt) {
        v8s af = afrag72(sub, rt, ks);
        acc[rt][0] = __builtin_amdgcn_mfma_f32_16x16x32_bf16(af, obf[0][ks], acc[rt][0], 0, 0, 0);
        acc[rt][1] = __builtin_amdgcn_mfma_f32_16x16x32_bf16(af, obf[1][ks], acc[rt][1], 0, 0, 0);
      }
    }
    pack_out(acc, P);
  };
  auto layer2 = [&](const float* b, uint32_t (&Pin)[8][2][2], uint32_t (&Pout)[8][2][2]) {
    v4f acc[8][2];
    bias_init(b, acc);
    #pragma unroll
    for (int ks = 0; ks < 4; ++ks) {
      v8s bf0 = bfrag_from(Pin, ks, 0), bf1 = bfrag_from(Pin, ks, 1);
      #pragma unroll
      for (int rt = 0; rt < 8; ++rt) {
        v8s af = afrag136(rt, ks);
        acc[rt][0] = __builtin_amdgcn_mfma_f32_16x16x32_bf16(af, bf0, acc[rt][0], 0, 0, 0);
        acc[rt][1] = __builtin_amdgcn_mfma_f32_16x16x32_bf16(af, bf1, acc[rt][1], 0, 0, 0);
      }
    }
    pack_out(acc, Pout);  // safe when Pout==Pin: all reads precede writes
  };

  uint32_t Pt[8][2][2];   // target-net activations
  uint32_t Pa[8][2][2];   // predictor-net activations

  __syncthreads();                      // bar0: W1 pair staged
  layer1(0,    b1t, Pt);
  layer1(9216, b1p, Pa);   __syncthreads();  // bar1
  stage128(Wall + 8192);   __syncthreads();  // bar2: W2t
  layer2(b2t, Pt, Pt);     __syncthreads();  // bar3
  stage128(Wall + 49152);  __syncthreads();  // bar4: W2p
  layer2(b2p, Pa, Pa);     __syncthreads();  // bar5
  stage128(Wall + 24576);  __syncthreads();  // bar6: W3t

  // ---- final layer: acc = (b3t-b3p) + W3t*H2t + (-W3p)*H2p == y_t - y_p ----
  v4f acc[8][2];
  #pragma unroll
  for (int rt = 0; rt < 8; ++rt) {
    float4 bt = *(const float4*)(b3t + rt * 16 + q * 4);
    float4 bp = *(const float4*)(b3p + rt * 16 + q * 4);
    v4f c; c[0] = bt.x - bp.x; c[1] = bt.y - bp.y; c[2] = bt.z - bp.z; c[3] = bt.w - bp.w;
    acc[rt][0] = c; acc[rt][1] = c;
  }
  #pragma unroll
  for (int ks = 0; ks < 4; ++ks) {
    v8s bf0 = bfrag_from(Pt, ks, 0), bf1 = bfrag_from(Pt, ks, 1);
    #pragma unroll
    for (int rt = 0; rt < 8; ++rt) {
      v8s af = afrag136(rt, ks);
      acc[rt][0] = __builtin_amdgcn_mfma_f32_16x16x32_bf16(af, bf0, acc[rt][0], 0, 0, 0);
      acc[rt][1] = __builtin_amdgcn_mfma_f32_16x16x32_bf16(af, bf1, acc[rt][1], 0, 0, 0);
    }
  }
  __syncthreads();                           // bar7
  stage128(Wall + 65536);  __syncthreads();  // bar8: W3n (pre-negated)
  #pragma unroll
  for (int ks = 0; ks < 4; ++ks) {
    v8s bf0 = bfrag_from(Pa, ks, 0), bf1 = bfrag_from(Pa, ks, 1);
    #pragma unroll
    for (int rt = 0; rt < 8; ++rt) {
      v8s af = afrag136(rt, ks);
      acc[rt][0] = __builtin_amdgcn_mfma_f32_16x16x32_bf16(af, bf0, acc[rt][0], 0, 0, 0);
      acc[rt][1] = __builtin_amdgcn_mfma_f32_16x16x32_bf16(af, bf1, acc[rt][1], 0, 0, 0);
    }
  }

  // ---- epilogue: reward = mean over 128 out-dims of diff^2 ----
  float p0 = 0.f, p1 = 0.f;
  #pragma unroll
  for (int rt = 0; rt < 8; ++rt) {
    v4f a0 = acc[rt][0], a1 = acc[rt][1];
    p0 += a0[0]*a0[0] + a0[1]*a0[1] + a0[2]*a0[2] + a0[3]*a0[3];
    p1 += a1[0]*a1[0] + a1[1]*a1[1] + a1[2]*a1[2] + a1[3]*a1[3];
  }
  p0 += __shfl_xor(p0, 32); p0 += __shfl_xor(p0, 16);
  p1 += __shfl_xor(p1, 32); p1 += __shfl_xor(p1, 16);
  float r0 = p0 * (1.0f / 128.0f), r1 = p1 * (1.0f / 128.0f);
  if (q == 0) {
    rewards[s0 + n]      = r0;
    rewards[s0 + 16 + n] = r1;
  }
  float s = r0 + r1, ss = r0 * r0 + r1 * r1;
  s  += __shfl_xor(s, 8);  s  += __shfl_xor(s, 4);  s  += __shfl_xor(s, 2);  s  += __shfl_xor(s, 1);
  ss += __shfl_xor(ss, 8); ss += __shfl_xor(ss, 4); ss += __shfl_xor(ss, 2); ss += __shfl_xor(ss, 1);
  if (lane == 0) { bs[wv] = s; bss[wv] = ss; }
  __syncthreads();                           // bar9
  if (t == 0) {
    atomicAdd(&sums[0], bs[0] + bs[1] + bs[2] + bs[3]);
    atomicAdd(&sums[1], bss[0] + bss[1] + bss[2] + bss[3]);
  }
}

// ---- normalize: Chan-merge with running stats ----
__global__ void rnd_norm(const float* __restrict__ rewards, const float* __restrict__ sums,
                         const float* __restrict__ rm, const float* __restrict__ rm2,
                         const float* __restrict__ rc, float* __restrict__ out) {
  float S = sums[0], SS = sums[1];
  float nb = (float)BATCH;
  float bm = S / nb;
  float bm2 = SS - nb * bm * bm;
  float cnt = rc[0];
  float newc = cnt + nb;
  float delta = bm - rm[0];
  float newmean = rm[0] + delta * nb / newc;
  float newm2 = rm2[0] + bm2 + delta * delta * cnt * nb / newc;
  float sd = (newc > 1.f) ? sqrtf(newm2 / (newc - 1.f)) : 1.f;
  float inv = 1.f / (sd + 1e-8f);
  int i = (blockIdx.x * 256 + threadIdx.x) * 4;
  float4 r = *(const float4*)(rewards + i);
  float4 o;
  o.x = (r.x - newmean) * inv; o.y = (r.y - newmean) * inv;
  o.z = (r.z - newmean) * inv; o.w = (r.w - newmean) * inv;
  *(float4*)(out + i) = o;
}

extern "C" void kernel_launch(void* const* d_in, const int* in_sizes, int n_in,
                              void* d_out, int out_size, void* d_ws, size_t ws_size,
                              hipStream_t stream) {
  const float* obs = (const float*)d_in[0];
  const float* rm  = (const float*)d_in[1];
  const float* rm2 = (const float*)d_in[2];
  const float* rc  = (const float*)d_in[3];
  const float* tW1 = (const float*)d_in[4];
  const float* tb1 = (const float*)d_in[5];
  const float* tW2 = (const float*)d_in[6];
  const float* tb2 = (const float*)d_in[7];
  const float* tW3 = (const float*)d_in[8];
  const float* tb3 = (const float*)d_in[9];
  const float* pW1 = (const float*)d_in[10];
  const float* pb1 = (const float*)d_in[11];
  const float* pW2 = (const float*)d_in[12];
  const float* pb2 = (const float*)d_in[13];
  const float* pW3 = (const float*)d_in[14];
  const float* pb3 = (const float*)d_in[15];

  float*    sums    = (float*)d_ws;
  float*    rewards = (float*)((char*)d_ws + 256);
  uint16_t* Wall    = (uint16_t*)((char*)d_ws + 256 + (size_t)BATCH * 4);

  rnd_prep<<<320, 256, 0, stream>>>(tW1, tW2, tW3, pW1, pW2, pW3, Wall, sums);
  rnd_main<<<BATCH / 128, 256, 0, stream>>>(obs, Wall, tb1, tb2, pb1, pb2, tb3, pb3,
                                            rewards, sums);
  rnd_norm<<<BATCH / 1024, 256, 0, stream>>>(rewards, sums, rm, rm2, rc, (float*)d_out);
}